// Round 6
// baseline (135.165 us; speedup 1.0000x reference)
//
#include <hip/hip_runtime.h>
#include <math.h>

// N_SRC=N_DST=10000, E=320000, T=4, C=64.
// Pipeline (memset + 4 launches):
//   memsetAsync : counts = 0
//   proj_kernel : LDS-tiled fp32 GEMM (64x64 tile, 4x4 micro-tile) + fused edge
//                 histogram (1 edge/thread, atomics hide under GEMM).
//     src blocks: h_srcT = (feat_src@u) transposed [node][c][t] (+ zero sentinel row)
//     dst blocks: h_base = feat_dst@u AND h_dst_v = feat_dst@v from one staged A-tile
//   scan        : exclusive scan -> offsets, cursor
//   scatter     : counting-sort edges by dst into packed int2 {src, bits(w)}
//   aggregate   : one wave per dst, depth-8 gather pipeline, fused sigmoid gate +
//                 LayerNorm + residual. No atomics.

__global__ __launch_bounds__(256) void proj_kernel(
    const float* __restrict__ feat_src, const float* __restrict__ feat_dst,
    const float* __restrict__ U, const float* __restrict__ V,
    const int* __restrict__ dst_idx, int E,
    float* __restrict__ h_srcT, float* __restrict__ h_base, float* __restrict__ h_dst_v,
    int* __restrict__ counts, int n_src, int n_dst) {
    __shared__ float sA[64 * 68];   // A-tile [64 rows][64 k], stride 68 (2-bank alias = free)
    __shared__ float sU[4096];      // U [k][c]
    __shared__ float sV[4096];      // V [k][c] (dst path only)
    int t = threadIdx.x, b = blockIdx.x;
    int nsb = (n_src * 4 + 63) >> 6;

    // fused histogram: one edge per thread (grid covers E exactly at 1250x256)
    for (int e = b * 256 + t; e < E; e += gridDim.x * 256)
        atomicAdd(&counts[dst_idx[e]], 1);
    if (b == 0) h_srcT[(size_t)n_src * 256 + t] = 0.f;   // sentinel row = zeros

    bool is_src = b < nsb;
    int rb = is_src ? b : b - nsb;
    int nrows = (is_src ? n_src : n_dst) * 4;
    int r0 = rb * 64;
    const float* A = is_src ? feat_src : feat_dst;

    // ---- stage W (and V for dst path) ----
    {
        const float4* U4 = (const float4*)U;
        float4* sU4 = (float4*)sU;
#pragma unroll
        for (int i = 0; i < 4; ++i) sU4[t + i * 256] = U4[t + i * 256];
        if (!is_src) {
            const float4* V4 = (const float4*)V;
            float4* sV4 = (float4*)sV;
#pragma unroll
            for (int i = 0; i < 4; ++i) sV4[t + i * 256] = V4[t + i * 256];
        }
    }
    // ---- stage A tile, coalesced ----
    {
        int row = t >> 4, chunk = t & 15;
#pragma unroll
        for (int p = 0; p < 4; ++p) {
            int rr = row + p * 16;
            int r = r0 + rr;
            if (r >= nrows) r = nrows - 1;
            float4 v = *(const float4*)(A + (size_t)r * 64 + chunk * 4);
            *(float4*)&sA[rr * 68 + chunk * 4] = v;
        }
    }
    __syncthreads();

    int rg = t >> 4;            // rows rg*4 .. rg*4+3
    int c4 = (t & 15) * 4;      // cols c4 .. c4+3

    if (is_src) {
        float acc[4][4];
#pragma unroll
        for (int j = 0; j < 4; ++j)
#pragma unroll
            for (int m = 0; m < 4; ++m) acc[j][m] = 0.f;
#pragma unroll 16
        for (int k = 0; k < 64; ++k) {
            float4 wu = *(const float4*)&sU[k * 64 + c4];
#pragma unroll
            for (int j = 0; j < 4; ++j) {
                float a = sA[(rg * 4 + j) * 68 + k];
                acc[j][0] = fmaf(a, wu.x, acc[j][0]);
                acc[j][1] = fmaf(a, wu.y, acc[j][1]);
                acc[j][2] = fmaf(a, wu.z, acc[j][2]);
                acc[j][3] = fmaf(a, wu.w, acc[j][3]);
            }
        }
        int node = (r0 >> 2) + rg;
        if (node < n_src) {
#pragma unroll
            for (int m = 0; m < 4; ++m) {
                float4 st;
                st.x = acc[0][m]; st.y = acc[1][m]; st.z = acc[2][m]; st.w = acc[3][m];
                *(float4*)&h_srcT[(size_t)node * 256 + (size_t)(c4 + m) * 4] = st;
            }
        }
    } else {
        float accU[4][4], accV[4][4];
#pragma unroll
        for (int j = 0; j < 4; ++j)
#pragma unroll
            for (int m = 0; m < 4; ++m) { accU[j][m] = 0.f; accV[j][m] = 0.f; }
#pragma unroll 8
        for (int k = 0; k < 64; ++k) {
            float4 wu = *(const float4*)&sU[k * 64 + c4];
            float4 wv = *(const float4*)&sV[k * 64 + c4];
#pragma unroll
            for (int j = 0; j < 4; ++j) {
                float a = sA[(rg * 4 + j) * 68 + k];
                accU[j][0] = fmaf(a, wu.x, accU[j][0]);
                accU[j][1] = fmaf(a, wu.y, accU[j][1]);
                accU[j][2] = fmaf(a, wu.z, accU[j][2]);
                accU[j][3] = fmaf(a, wu.w, accU[j][3]);
                accV[j][0] = fmaf(a, wv.x, accV[j][0]);
                accV[j][1] = fmaf(a, wv.y, accV[j][1]);
                accV[j][2] = fmaf(a, wv.z, accV[j][2]);
                accV[j][3] = fmaf(a, wv.w, accV[j][3]);
            }
        }
#pragma unroll
        for (int j = 0; j < 4; ++j) {
            int r = r0 + rg * 4 + j;
            if (r < nrows) {
                float4 su, sv;
                su.x = accU[j][0]; su.y = accU[j][1]; su.z = accU[j][2]; su.w = accU[j][3];
                sv.x = accV[j][0]; sv.y = accV[j][1]; sv.z = accV[j][2]; sv.w = accV[j][3];
                *(float4*)&h_base [(size_t)r * 64 + c4] = su;
                *(float4*)&h_dst_v[(size_t)r * 64 + c4] = sv;
            }
        }
    }
}

__global__ __launch_bounds__(1024) void scan_kernel(
    const int* __restrict__ counts, int n,
    int* __restrict__ offsets, int* __restrict__ cursor) {
    __shared__ int partial[1024];
    int tid = threadIdx.x;
    int chunk = (n + 1023) >> 10;
    int begin = tid * chunk;
    int end = begin + chunk < n ? begin + chunk : n;
    int s = 0;
    for (int j = begin; j < end; ++j) s += counts[j];
    partial[tid] = s;
    __syncthreads();
    for (int off = 1; off < 1024; off <<= 1) {
        int add = (tid >= off) ? partial[tid - off] : 0;
        __syncthreads();
        partial[tid] += add;
        __syncthreads();
    }
    int run = (tid > 0) ? partial[tid - 1] : 0;
    for (int j = begin; j < end; ++j) {
        offsets[j] = run;
        cursor[j] = run;
        run += counts[j];
    }
    if (tid == 0) offsets[n] = partial[1023];
}

__global__ void scatter_kernel(
    const int* __restrict__ src_idx, const int* __restrict__ dst_idx,
    const float* __restrict__ ew, int E, int* __restrict__ cursor,
    int2* __restrict__ es) {
    int e = blockIdx.x * blockDim.x + threadIdx.x;
    if (e < E) {
        int d = dst_idx[e];
        int pos = atomicAdd(&cursor[d], 1);
        es[pos] = make_int2(src_idx[e], __float_as_int(ew[e]));
    }
}

// One wave per dst node; lane c holds float4 over t. Depth-8 ping-pong gather pipeline.
__global__ __launch_bounds__(256) void aggregate_kernel(
    const float4* __restrict__ h_srcT,   // [(n_src+1)*64] float4s: node*64 + c
    const float* __restrict__ h_dst_v, const float* __restrict__ h_base,
    const float* __restrict__ feat_dst, const float* __restrict__ weight_e,
    const int* __restrict__ offsets, const int2* __restrict__ es,
    const float* __restrict__ gamma, const float* __restrict__ beta,
    float* __restrict__ out, int n_src) {
    int tid = threadIdx.x;
    int w = tid >> 6, c = tid & 63;
    int d = blockIdx.x * 4 + w;
    size_t rb = (size_t)d * 256;

    float wec = weight_e[c];
    float acc0 = h_base[rb +   0 + c], acc1 = h_base[rb +  64 + c];
    float acc2 = h_base[rb + 128 + c], acc3 = h_base[rb + 192 + c];
    const float nl2e = -1.44269504f;
    float hw0 = h_dst_v[rb +   0 + c] * wec * nl2e;
    float hw1 = h_dst_v[rb +  64 + c] * wec * nl2e;
    float hw2 = h_dst_v[rb + 128 + c] * wec * nl2e;
    float hw3 = h_dst_v[rb + 192 + c] * wec * nl2e;

    int e0 = offsets[d], e1 = offsets[d + 1];

    // masked slots gather the zeroed sentinel row (hs=0 -> contribution 0, any w)
    float4 hA[8]; float wA[8];
#pragma unroll
    for (int i = 0; i < 8; ++i) {
        int ee = e0 + i;
        int2 ev = (ee < e1) ? es[ee] : make_int2(n_src, 0);
        wA[i] = __int_as_float(ev.y);
        hA[i] = h_srcT[(size_t)ev.x * 64 + c];
    }

    for (int base = e0; base < e1; base += 8) {
        float4 hB[8]; float wB[8];
#pragma unroll
        for (int i = 0; i < 8; ++i) {
            int ee = base + 8 + i;
            int2 ev = (ee < e1) ? es[ee] : make_int2(n_src, 0);
            wB[i] = __int_as_float(ev.y);
            hB[i] = h_srcT[(size_t)ev.x * 64 + c];
        }
#pragma unroll
        for (int i = 0; i < 8; ++i) {
            float ww = wA[i];
            float4 hs = hA[i];
            float g0 = __builtin_amdgcn_rcpf(1.f + __builtin_amdgcn_exp2f(hs.x * (hw0 * ww)));
            float g1 = __builtin_amdgcn_rcpf(1.f + __builtin_amdgcn_exp2f(hs.y * (hw1 * ww)));
            float g2 = __builtin_amdgcn_rcpf(1.f + __builtin_amdgcn_exp2f(hs.z * (hw2 * ww)));
            float g3 = __builtin_amdgcn_rcpf(1.f + __builtin_amdgcn_exp2f(hs.w * (hw3 * ww)));
            acc0 = fmaf(hs.x, g0, acc0);
            acc1 = fmaf(hs.y, g1, acc1);
            acc2 = fmaf(hs.z, g2, acc2);
            acc3 = fmaf(hs.w, g3, acc3);
        }
#pragma unroll
        for (int i = 0; i < 8; ++i) { hA[i] = hB[i]; wA[i] = wB[i]; }
    }

    // fused LayerNorm (over c = lanes, per t) + residual
    float s10 = acc0, s11 = acc1, s12 = acc2, s13 = acc3;
    float s20 = acc0 * acc0, s21 = acc1 * acc1, s22 = acc2 * acc2, s23 = acc3 * acc3;
#pragma unroll
    for (int off = 32; off >= 1; off >>= 1) {
        s10 += __shfl_xor(s10, off, 64); s20 += __shfl_xor(s20, off, 64);
        s11 += __shfl_xor(s11, off, 64); s21 += __shfl_xor(s21, off, 64);
        s12 += __shfl_xor(s12, off, 64); s22 += __shfl_xor(s22, off, 64);
        s13 += __shfl_xor(s13, off, 64); s23 += __shfl_xor(s23, off, 64);
    }
    float gm = gamma[c], bt = beta[c];
    const float inv64 = 1.f / 64.f;
#pragma unroll
    for (int t = 0; t < 4; ++t) {
        float acc = t == 0 ? acc0 : t == 1 ? acc1 : t == 2 ? acc2 : acc3;
        float s1  = t == 0 ? s10  : t == 1 ? s11  : t == 2 ? s12  : s13;
        float s2  = t == 0 ? s20  : t == 1 ? s21  : t == 2 ? s22  : s23;
        float mean = s1 * inv64;
        float var  = s2 * inv64 - mean * mean;
        float inv  = rsqrtf(var + 1e-5f);
        out[rb + t * 64 + c] = (acc - mean) * inv * gm + bt + feat_dst[rb + t * 64 + c];
    }
}

extern "C" void kernel_launch(void* const* d_in, const int* in_sizes, int n_in,
                              void* d_out, int out_size, void* d_ws, size_t ws_size,
                              hipStream_t stream) {
    const float* feat_src    = (const float*)d_in[0];
    const float* feat_dst    = (const float*)d_in[1];
    const float* edge_weight = (const float*)d_in[2];
    const float* weight_e    = (const float*)d_in[3];
    const float* u           = (const float*)d_in[4];
    const float* v           = (const float*)d_in[5];
    const float* ln_gamma    = (const float*)d_in[6];
    const float* ln_beta     = (const float*)d_in[7];
    const int*   src_idx     = (const int*)d_in[8];
    const int*   dst_idx     = (const int*)d_in[9];
    float* out = (float*)d_out;

    int E     = in_sizes[2];
    int n_src = in_sizes[0] / 256;   // N_SRC (T*C = 256)
    int n_dst = in_sizes[1] / 256;   // N_DST

    // Workspace layout
    float* h_srcT    = (float*)d_ws;                            // (n_src+1)*256
    float* h_base    = h_srcT + (size_t)(n_src + 1) * 256;      // n_dst*256
    float* h_dst_v   = h_base + (size_t)n_dst * 256;            // n_dst*256
    int2*  es        = (int2*)(h_dst_v + (size_t)n_dst * 256);  // E (+ slack)
    int*   counts    = (int*)(es + E + 16);                     // n_dst
    int*   offsets   = counts + n_dst;                          // n_dst+1
    int*   cursor    = offsets + n_dst + 1;                     // n_dst

    int nsb = (n_src * 4 + 63) / 64;   // 625
    int ndb = (n_dst * 4 + 63) / 64;   // 625

    hipMemsetAsync(counts, 0, (size_t)n_dst * sizeof(int), stream);
    proj_kernel<<<nsb + ndb, 256, 0, stream>>>(feat_src, feat_dst, u, v,
                                               dst_idx, E,
                                               h_srcT, h_base, h_dst_v,
                                               counts, n_src, n_dst);
    scan_kernel<<<1, 1024, 0, stream>>>(counts, n_dst, offsets, cursor);
    scatter_kernel<<<(E + 255) / 256, 256, 0, stream>>>(src_idx, dst_idx, edge_weight, E,
                                                        cursor, es);
    aggregate_kernel<<<n_dst / 4, 256, 0, stream>>>((const float4*)h_srcT, h_dst_v, h_base,
                                                    feat_dst, weight_e,
                                                    offsets, es,
                                                    ln_gamma, ln_beta, out, n_src);
}

// Round 7
// 114.519 us; speedup vs baseline: 1.1803x; 1.1803x over previous
//
#include <hip/hip_runtime.h>
#include <math.h>

// N_SRC=N_DST=10000, E=320000, T=4, C=64.
// Pipeline (memset + 4 launches):
//   memsetAsync : counts = 0
//   proj_kernel : LDS-tiled fp32 GEMM (64x64 tile, 4x4 micro-tile) + fused edge
//                 histogram (atomics hide under GEMM).
//     src blocks: h_srcT = bf16[(feat_src@u)] transposed [node][c][t] (+ zero sentinel)
//     dst blocks: h_base = feat_dst@u AND h_dst_v = feat_dst@v from one staged A-tile
//   scan        : exclusive scan -> offsets, cursor
//   scatter     : counting-sort edges by dst into packed int2 {src, bits(w)}
//   aggregate   : TWO waves per dst node (half the edge list each, depth-4 pipeline),
//                 partials exchanged via LDS, fused sigmoid gate + LN + residual.

__device__ __forceinline__ unsigned short f2bf(float f) {
    unsigned u = __float_as_uint(f);
    return (unsigned short)((u + 0x7fffu + ((u >> 16) & 1u)) >> 16);   // RNE
}

__global__ __launch_bounds__(256) void proj_kernel(
    const float* __restrict__ feat_src, const float* __restrict__ feat_dst,
    const float* __restrict__ U, const float* __restrict__ V,
    const int* __restrict__ dst_idx, int E,
    ushort4* __restrict__ h_srcT, float* __restrict__ h_base, float* __restrict__ h_dst_v,
    int* __restrict__ counts, int n_src, int n_dst) {
    __shared__ float sA[64 * 68];   // A-tile [64 rows][64 k], stride 68 (2-bank alias = free)
    __shared__ float sU[4096];      // U [k][c]
    __shared__ float sV[4096];      // V [k][c] (dst path only)
    int t = threadIdx.x, b = blockIdx.x;
    int nsb = (n_src * 4 + 63) >> 6;

    // fused histogram: one edge per thread (grid covers E exactly at 1250x256)
    for (int e = b * 256 + t; e < E; e += gridDim.x * 256)
        atomicAdd(&counts[dst_idx[e]], 1);
    if (b == 0 && t < 64) h_srcT[(size_t)n_src * 64 + t] = make_ushort4(0, 0, 0, 0);

    bool is_src = b < nsb;
    int rb = is_src ? b : b - nsb;
    int nrows = (is_src ? n_src : n_dst) * 4;
    int r0 = rb * 64;
    const float* A = is_src ? feat_src : feat_dst;

    // ---- stage W (and V for dst path) ----
    {
        const float4* U4 = (const float4*)U;
        float4* sU4 = (float4*)sU;
#pragma unroll
        for (int i = 0; i < 4; ++i) sU4[t + i * 256] = U4[t + i * 256];
        if (!is_src) {
            const float4* V4 = (const float4*)V;
            float4* sV4 = (float4*)sV;
#pragma unroll
            for (int i = 0; i < 4; ++i) sV4[t + i * 256] = V4[t + i * 256];
        }
    }
    // ---- stage A tile, coalesced ----
    {
        int row = t >> 4, chunk = t & 15;
#pragma unroll
        for (int p = 0; p < 4; ++p) {
            int rr = row + p * 16;
            int r = r0 + rr;
            if (r >= nrows) r = nrows - 1;
            float4 v = *(const float4*)(A + (size_t)r * 64 + chunk * 4);
            *(float4*)&sA[rr * 68 + chunk * 4] = v;
        }
    }
    __syncthreads();

    int rg = t >> 4;            // rows rg*4 .. rg*4+3
    int c4 = (t & 15) * 4;      // cols c4 .. c4+3

    if (is_src) {
        float acc[4][4];
#pragma unroll
        for (int j = 0; j < 4; ++j)
#pragma unroll
            for (int m = 0; m < 4; ++m) acc[j][m] = 0.f;
#pragma unroll 16
        for (int k = 0; k < 64; ++k) {
            float4 wu = *(const float4*)&sU[k * 64 + c4];
#pragma unroll
            for (int j = 0; j < 4; ++j) {
                float a = sA[(rg * 4 + j) * 68 + k];
                acc[j][0] = fmaf(a, wu.x, acc[j][0]);
                acc[j][1] = fmaf(a, wu.y, acc[j][1]);
                acc[j][2] = fmaf(a, wu.z, acc[j][2]);
                acc[j][3] = fmaf(a, wu.w, acc[j][3]);
            }
        }
        int node = (r0 >> 2) + rg;
        if (node < n_src) {
#pragma unroll
            for (int m = 0; m < 4; ++m) {
                ushort4 st;
                st.x = f2bf(acc[0][m]); st.y = f2bf(acc[1][m]);
                st.z = f2bf(acc[2][m]); st.w = f2bf(acc[3][m]);
                h_srcT[(size_t)node * 64 + c4 + m] = st;   // [node][c][t], 8B/lane
            }
        }
    } else {
        float accU[4][4], accV[4][4];
#pragma unroll
        for (int j = 0; j < 4; ++j)
#pragma unroll
            for (int m = 0; m < 4; ++m) { accU[j][m] = 0.f; accV[j][m] = 0.f; }
#pragma unroll 8
        for (int k = 0; k < 64; ++k) {
            float4 wu = *(const float4*)&sU[k * 64 + c4];
            float4 wv = *(const float4*)&sV[k * 64 + c4];
#pragma unroll
            for (int j = 0; j < 4; ++j) {
                float a = sA[(rg * 4 + j) * 68 + k];
                accU[j][0] = fmaf(a, wu.x, accU[j][0]);
                accU[j][1] = fmaf(a, wu.y, accU[j][1]);
                accU[j][2] = fmaf(a, wu.z, accU[j][2]);
                accU[j][3] = fmaf(a, wu.w, accU[j][3]);
                accV[j][0] = fmaf(a, wv.x, accV[j][0]);
                accV[j][1] = fmaf(a, wv.y, accV[j][1]);
                accV[j][2] = fmaf(a, wv.z, accV[j][2]);
                accV[j][3] = fmaf(a, wv.w, accV[j][3]);
            }
        }
#pragma unroll
        for (int j = 0; j < 4; ++j) {
            int r = r0 + rg * 4 + j;
            if (r < nrows) {
                float4 su, sv;
                su.x = accU[j][0]; su.y = accU[j][1]; su.z = accU[j][2]; su.w = accU[j][3];
                sv.x = accV[j][0]; sv.y = accV[j][1]; sv.z = accV[j][2]; sv.w = accV[j][3];
                *(float4*)&h_base [(size_t)r * 64 + c4] = su;
                *(float4*)&h_dst_v[(size_t)r * 64 + c4] = sv;
            }
        }
    }
}

__global__ __launch_bounds__(1024) void scan_kernel(
    const int* __restrict__ counts, int n,
    int* __restrict__ offsets, int* __restrict__ cursor) {
    __shared__ int partial[1024];
    int tid = threadIdx.x;
    int chunk = (n + 1023) >> 10;
    int begin = tid * chunk;
    int end = begin + chunk < n ? begin + chunk : n;
    int s = 0;
    for (int j = begin; j < end; ++j) s += counts[j];
    partial[tid] = s;
    __syncthreads();
    for (int off = 1; off < 1024; off <<= 1) {
        int add = (tid >= off) ? partial[tid - off] : 0;
        __syncthreads();
        partial[tid] += add;
        __syncthreads();
    }
    int run = (tid > 0) ? partial[tid - 1] : 0;
    for (int j = begin; j < end; ++j) {
        offsets[j] = run;
        cursor[j] = run;
        run += counts[j];
    }
    if (tid == 0) offsets[n] = partial[1023];
}

__global__ void scatter_kernel(
    const int* __restrict__ src_idx, const int* __restrict__ dst_idx,
    const float* __restrict__ ew, int E, int* __restrict__ cursor,
    int2* __restrict__ es) {
    int e = blockIdx.x * blockDim.x + threadIdx.x;
    if (e < E) {
        int d = dst_idx[e];
        int pos = atomicAdd(&cursor[d], 1);
        es[pos] = make_int2(src_idx[e], __float_as_int(ew[e]));
    }
}

// 2 dst nodes per block; 2 waves per node, each takes half the edge list.
// Wave h of a node owns output rows t={2h,2h+1}; partial sums for the other
// t-pair are exchanged through LDS. Depth-4 ping-pong gather pipeline, bf16 h_srcT.
__global__ __launch_bounds__(256) void aggregate_kernel(
    const ushort4* __restrict__ h_srcT,  // [(n_src+1)*64]: node*64 + c -> 4x bf16 (t)
    const float* __restrict__ h_dst_v, const float* __restrict__ h_base,
    const float* __restrict__ feat_dst, const float* __restrict__ weight_e,
    const int* __restrict__ offsets, const int2* __restrict__ es,
    const float* __restrict__ gamma, const float* __restrict__ beta,
    float* __restrict__ out, int n_src) {
    __shared__ float xbuf[2][2][2][64];   // [node_in_blk][writer_half][pair][c]
    int tid = threadIdx.x;
    int wid = tid >> 6, c = tid & 63;
    int nb = wid >> 1;         // node within block
    int h  = wid & 1;          // which half of the edge list
    int d  = blockIdx.x * 2 + nb;
    size_t rb = (size_t)d * 256;

    float wec = weight_e[c];
    const float nl2e = -1.44269504f;
    float hw0 = h_dst_v[rb +   0 + c] * wec * nl2e;
    float hw1 = h_dst_v[rb +  64 + c] * wec * nl2e;
    float hw2 = h_dst_v[rb + 128 + c] * wec * nl2e;
    float hw3 = h_dst_v[rb + 192 + c] * wec * nl2e;

    int e0 = offsets[d], e1 = offsets[d + 1];
    int mid = e0 + ((e1 - e0) >> 1);
    int ea = h ? mid : e0;
    int eb = h ? e1  : mid;

    float acc0 = 0.f, acc1 = 0.f, acc2 = 0.f, acc3 = 0.f;

    // masked slots gather the zeroed sentinel row (hs=0 -> contribution 0)
    ushort4 hA[4]; float wA[4];
#pragma unroll
    for (int i = 0; i < 4; ++i) {
        int ee = ea + i;
        int2 ev = (ee < eb) ? es[ee] : make_int2(n_src, 0);
        wA[i] = __int_as_float(ev.y);
        hA[i] = h_srcT[(size_t)ev.x * 64 + c];
    }

    for (int base = ea; base < eb; base += 4) {
        ushort4 hB[4]; float wB[4];
#pragma unroll
        for (int i = 0; i < 4; ++i) {
            int ee = base + 4 + i;
            int2 ev = (ee < eb) ? es[ee] : make_int2(n_src, 0);
            wB[i] = __int_as_float(ev.y);
            hB[i] = h_srcT[(size_t)ev.x * 64 + c];
        }
#pragma unroll
        for (int i = 0; i < 4; ++i) {
            float ww = wA[i];
            float x0 = __uint_as_float((unsigned)hA[i].x << 16);
            float x1 = __uint_as_float((unsigned)hA[i].y << 16);
            float x2 = __uint_as_float((unsigned)hA[i].z << 16);
            float x3 = __uint_as_float((unsigned)hA[i].w << 16);
            float g0 = __builtin_amdgcn_rcpf(1.f + __builtin_amdgcn_exp2f(x0 * (hw0 * ww)));
            float g1 = __builtin_amdgcn_rcpf(1.f + __builtin_amdgcn_exp2f(x1 * (hw1 * ww)));
            float g2 = __builtin_amdgcn_rcpf(1.f + __builtin_amdgcn_exp2f(x2 * (hw2 * ww)));
            float g3 = __builtin_amdgcn_rcpf(1.f + __builtin_amdgcn_exp2f(x3 * (hw3 * ww)));
            acc0 = fmaf(x0, g0, acc0);
            acc1 = fmaf(x1, g1, acc1);
            acc2 = fmaf(x2, g2, acc2);
            acc3 = fmaf(x3, g3, acc3);
        }
#pragma unroll
        for (int i = 0; i < 4; ++i) { hA[i] = hB[i]; wA[i] = wB[i]; }
    }

    // exchange the t-pair this wave does NOT own
    xbuf[nb][h][0][c] = h ? acc0 : acc2;
    xbuf[nb][h][1][c] = h ? acc1 : acc3;
    __syncthreads();
    float pa = xbuf[nb][1 - h][0][c];
    float pb = xbuf[nb][1 - h][1][c];

    int ta = 2 * h, tb = 2 * h + 1;
    float fa = (h ? acc2 : acc0) + pa + h_base[rb + ta * 64 + c];
    float fb = (h ? acc3 : acc1) + pb + h_base[rb + tb * 64 + c];

    // LayerNorm over c (one wave) per owned row + residual
    float s1a = fa, s2a = fa * fa, s1b = fb, s2b = fb * fb;
#pragma unroll
    for (int off = 32; off >= 1; off >>= 1) {
        s1a += __shfl_xor(s1a, off, 64); s2a += __shfl_xor(s2a, off, 64);
        s1b += __shfl_xor(s1b, off, 64); s2b += __shfl_xor(s2b, off, 64);
    }
    float gm = gamma[c], bt = beta[c];
    const float inv64 = 1.f / 64.f;
    float ma = s1a * inv64, va = s2a * inv64 - ma * ma;
    float mb = s1b * inv64, vb = s2b * inv64 - mb * mb;
    out[rb + ta * 64 + c] = (fa - ma) * rsqrtf(va + 1e-5f) * gm + bt + feat_dst[rb + ta * 64 + c];
    out[rb + tb * 64 + c] = (fb - mb) * rsqrtf(vb + 1e-5f) * gm + bt + feat_dst[rb + tb * 64 + c];
}

extern "C" void kernel_launch(void* const* d_in, const int* in_sizes, int n_in,
                              void* d_out, int out_size, void* d_ws, size_t ws_size,
                              hipStream_t stream) {
    const float* feat_src    = (const float*)d_in[0];
    const float* feat_dst    = (const float*)d_in[1];
    const float* edge_weight = (const float*)d_in[2];
    const float* weight_e    = (const float*)d_in[3];
    const float* u           = (const float*)d_in[4];
    const float* v           = (const float*)d_in[5];
    const float* ln_gamma    = (const float*)d_in[6];
    const float* ln_beta     = (const float*)d_in[7];
    const int*   src_idx     = (const int*)d_in[8];
    const int*   dst_idx     = (const int*)d_in[9];
    float* out = (float*)d_out;

    int E     = in_sizes[2];
    int n_src = in_sizes[0] / 256;   // N_SRC (T*C = 256)
    int n_dst = in_sizes[1] / 256;   // N_DST

    // Workspace layout
    ushort4* h_srcT  = (ushort4*)d_ws;                               // (n_src+1)*64 ushort4
    float* h_base    = (float*)(h_srcT + (size_t)(n_src + 1) * 64);  // n_dst*256
    float* h_dst_v   = h_base + (size_t)n_dst * 256;                 // n_dst*256
    int2*  es        = (int2*)(h_dst_v + (size_t)n_dst * 256);       // E (+ slack)
    int*   counts    = (int*)(es + E + 16);                          // n_dst
    int*   offsets   = counts + n_dst;                               // n_dst+1
    int*   cursor    = offsets + n_dst + 1;                          // n_dst

    int nsb = (n_src * 4 + 63) / 64;   // 625
    int ndb = (n_dst * 4 + 63) / 64;   // 625

    hipMemsetAsync(counts, 0, (size_t)n_dst * sizeof(int), stream);
    proj_kernel<<<nsb + ndb, 256, 0, stream>>>(feat_src, feat_dst, u, v,
                                               dst_idx, E,
                                               h_srcT, h_base, h_dst_v,
                                               counts, n_src, n_dst);
    scan_kernel<<<1, 1024, 0, stream>>>(counts, n_dst, offsets, cursor);
    scatter_kernel<<<(E + 255) / 256, 256, 0, stream>>>(src_idx, dst_idx, edge_weight, E,
                                                        cursor, es);
    aggregate_kernel<<<n_dst / 2, 256, 0, stream>>>(h_srcT, h_dst_v, h_base,
                                                    feat_dst, weight_e,
                                                    offsets, es,
                                                    ln_gamma, ln_beta, out, n_src);
}